// Round 1
// baseline (768.779 us; speedup 1.0000x reference)
//
#include <hip/hip_runtime.h>
#include <stdint.h>

#define N_NODES 200000
#define C_INN   256
#define C_MIDD  64
#define KNB     27

typedef unsigned short u16;
typedef __attribute__((ext_vector_type(8))) short short8;
typedef __attribute__((ext_vector_type(4))) float floatx4;

__device__ inline float bf2f(u16 u) {
  union { uint32_t i; float f; } v; v.i = ((uint32_t)u) << 16; return v.f;
}
__device__ inline u16 f2bf(float f) {
  union { float f; uint32_t i; } v; v.f = f;
  uint32_t lsb = (v.i >> 16) & 1u;
  uint32_t r = v.i + 0x7fffu + lsb;
  return (u16)(r >> 16);
}

// ---------------------------------------------------------------------------
// prep: zero stat accumulators; transpose+cast weights to bf16 B-operand form
//   w1t[d][k] (64x256), w2t[kn][d][c] (27x64x64), w3t[d][k] (256x64)
// ---------------------------------------------------------------------------
__global__ void prep_kernel(const float* __restrict__ W1, const float* __restrict__ W2,
                            const float* __restrict__ W3,
                            u16* __restrict__ w1t, u16* __restrict__ w2t,
                            u16* __restrict__ w3t, float* __restrict__ stats) {
  int tid = blockIdx.x * blockDim.x + threadIdx.x;
  int nth = gridDim.x * blockDim.x;
  for (int i = tid; i < 1536; i += nth) stats[i] = 0.f;
  for (int i = tid; i < 256 * 64; i += nth) {        // w1t[d*256+k] = W1[k][d]
    int d = i >> 8, k = i & 255;
    w1t[i] = f2bf(W1[k * 64 + d]);
  }
  for (int i = tid; i < 27 * 64 * 64; i += nth) {    // w2t[kn][d][c] = W2[kn][c][d]
    int kn = i >> 12, r = i & 4095, d = r >> 6, c = r & 63;
    w2t[i] = f2bf(W2[kn * 4096 + c * 64 + d]);
  }
  for (int i = tid; i < 256 * 64; i += nth) {        // w3t[d*64+k] = W3[k][d]
    int d = i >> 6, k = i & 63;
    w3t[i] = f2bf(W3[k * 256 + d]);
  }
}

// ---------------------------------------------------------------------------
// gemm1: y1[N,64] (bf16, raw pre-BN) = x[N,256] @ W1
// block: 256 thr (4 waves), 64-row tile, K chunked 2x128. LDS stride 136 (odd granule).
// ---------------------------------------------------------------------------
#define PAD1 136
__global__ __launch_bounds__(256) void gemm1_kernel(const float* __restrict__ x,
                                                    const u16* __restrict__ w1t,
                                                    u16* __restrict__ y1) {
  __shared__ u16 Als[64 * PAD1];
  __shared__ u16 Bls[64 * PAD1];
  int t = threadIdx.x;
  long long rowBase = (long long)blockIdx.x * 64;
  int w = t >> 6, lane = t & 63;
  int m = lane & 15, q = lane >> 4;
  floatx4 acc[4] = {};

  for (int kh = 0; kh < 2; kh++) {
    if (kh) __syncthreads();
    // A: 64 rows x 128 f32 -> bf16.  2048 float4 chunks
    #pragma unroll
    for (int j = 0; j < 8; j++) {
      int lin = j * 256 + t;
      int r = lin >> 5, c4 = lin & 31;
      floatx4 v = ((const floatx4*)x)[(rowBase + r) * 64 + kh * 32 + c4];
      ushort4 u;
      u.x = f2bf(v[0]); u.y = f2bf(v[1]); u.z = f2bf(v[2]); u.w = f2bf(v[3]);
      *(ushort4*)&Als[r * PAD1 + c4 * 4] = u;
    }
    // B: w1t 64 n-rows x 128 k  -> 1024 16B chunks
    #pragma unroll
    for (int j = 0; j < 4; j++) {
      int lin = j * 256 + t;
      int n = lin >> 4, c8 = lin & 15;
      uint4 u = ((const uint4*)w1t)[n * 32 + kh * 16 + c8];
      *(uint4*)&Bls[n * PAD1 + c8 * 8] = u;
    }
    __syncthreads();
    #pragma unroll
    for (int kc = 0; kc < 4; kc++) {
      short8 af = *(const short8*)&Als[(w * 16 + m) * PAD1 + kc * 32 + q * 8];
      #pragma unroll
      for (int tt = 0; tt < 4; tt++) {
        short8 bf = *(const short8*)&Bls[(tt * 16 + m) * PAD1 + kc * 32 + q * 8];
        acc[tt] = __builtin_amdgcn_mfma_f32_16x16x32_bf16(af, bf, acc[tt], 0, 0, 0);
      }
    }
  }
  long long base = rowBase + w * 16;
  #pragma unroll
  for (int tt = 0; tt < 4; tt++)
    #pragma unroll
    for (int r = 0; r < 4; r++)
      y1[(base + q * 4 + r) * 64 + tt * 16 + m] = f2bf(acc[tt][r]);
}

// ---------------------------------------------------------------------------
// gemm2: y2[N,64] (bf16 raw) = gather(h1, neigh) . W2   (27-slab K loop)
// ---------------------------------------------------------------------------
#define PAD2 72
__global__ __launch_bounds__(256) void gemm2_kernel(const u16* __restrict__ h1,
                                                    const int* __restrict__ neigh,
                                                    const u16* __restrict__ w2t,
                                                    u16* __restrict__ y2) {
  __shared__ u16 Als[64 * PAD2];
  __shared__ u16 Bls[64 * PAD2];
  __shared__ int nidx[64 * 27];
  int t = threadIdx.x;
  long long rowBase = (long long)blockIdx.x * 64;
  #pragma unroll
  for (int j = 0; j < 7; j++) {
    int lin = j * 256 + t;
    if (lin < 64 * 27) nidx[lin] = neigh[rowBase * 27 + lin];
  }
  int w = t >> 6, lane = t & 63;
  int m = lane & 15, q = lane >> 4;
  floatx4 acc[4] = {};

  for (int k = 0; k < KNB; k++) {
    __syncthreads();
    // gather A rows (64 x 128B) + W2 slab (8KB): 512+512 uint4 chunks
    #pragma unroll
    for (int j = 0; j < 2; j++) {
      int lin = j * 256 + t;
      int r = lin >> 3, c8 = lin & 7;
      long long src = (long long)nidx[r * 27 + k] * 8 + c8;
      *(uint4*)&Als[r * PAD2 + c8 * 8] = ((const uint4*)h1)[src];
      *(uint4*)&Bls[r * PAD2 + c8 * 8] = ((const uint4*)w2t)[k * 512 + lin];
    }
    __syncthreads();
    #pragma unroll
    for (int kc = 0; kc < 2; kc++) {
      short8 af = *(const short8*)&Als[(w * 16 + m) * PAD2 + kc * 32 + q * 8];
      #pragma unroll
      for (int tt = 0; tt < 4; tt++) {
        short8 bf = *(const short8*)&Bls[(tt * 16 + m) * PAD2 + kc * 32 + q * 8];
        acc[tt] = __builtin_amdgcn_mfma_f32_16x16x32_bf16(af, bf, acc[tt], 0, 0, 0);
      }
    }
  }
  long long base = rowBase + w * 16;
  #pragma unroll
  for (int tt = 0; tt < 4; tt++)
    #pragma unroll
    for (int r = 0; r < 4; r++)
      y2[(base + q * 4 + r) * 64 + tt * 16 + m] = f2bf(acc[tt][r]);
}

// ---------------------------------------------------------------------------
// gemm3: y3[N,256] (fp32, raw, into d_out) = h2[N,64] @ W3
// ---------------------------------------------------------------------------
#define PAD3 72
__global__ __launch_bounds__(256) void gemm3_kernel(const u16* __restrict__ h2,
                                                    const u16* __restrict__ w3t,
                                                    float* __restrict__ y3) {
  __shared__ u16 Als[64 * PAD3];
  __shared__ u16 Bls[256 * PAD3];
  int t = threadIdx.x;
  long long rowBase = (long long)blockIdx.x * 64;
  #pragma unroll
  for (int j = 0; j < 2; j++) {   // A: 64x64 bf16 = 512 chunks
    int lin = j * 256 + t;
    int r = lin >> 3, c8 = lin & 7;
    *(uint4*)&Als[r * PAD3 + c8 * 8] = ((const uint4*)h2)[rowBase * 8 + lin];
  }
  #pragma unroll
  for (int j = 0; j < 8; j++) {   // B: 256x64 bf16 = 2048 chunks
    int lin = j * 256 + t;
    int n = lin >> 3, c8 = lin & 7;
    *(uint4*)&Bls[n * PAD3 + c8 * 8] = ((const uint4*)w3t)[lin];
  }
  __syncthreads();
  int w = t >> 6, lane = t & 63;
  int m = lane & 15, q = lane >> 4;
  floatx4 acc[16] = {};
  short8 af0 = *(const short8*)&Als[(w * 16 + m) * PAD3 + q * 8];
  short8 af1 = *(const short8*)&Als[(w * 16 + m) * PAD3 + 32 + q * 8];
  #pragma unroll
  for (int tt = 0; tt < 16; tt++) {
    short8 b0 = *(const short8*)&Bls[(tt * 16 + m) * PAD3 + q * 8];
    short8 b1 = *(const short8*)&Bls[(tt * 16 + m) * PAD3 + 32 + q * 8];
    acc[tt] = __builtin_amdgcn_mfma_f32_16x16x32_bf16(af0, b0, acc[tt], 0, 0, 0);
    acc[tt] = __builtin_amdgcn_mfma_f32_16x16x32_bf16(af1, b1, acc[tt], 0, 0, 0);
  }
  long long base = rowBase + w * 16;
  #pragma unroll
  for (int tt = 0; tt < 16; tt++)
    #pragma unroll
    for (int r = 0; r < 4; r++)
      y3[(base + q * 4 + r) * 256 + tt * 16 + m] = acc[tt][r];
}

// ---------------------------------------------------------------------------
// per-channel sum / sumsq  (sums[0..C)=sum, sums[C..2C)=sumsq)
// ---------------------------------------------------------------------------
template <int C, bool BF>
__global__ __launch_bounds__(256) void stats_kernel(const void* __restrict__ yv,
                                                    float* __restrict__ sums) {
  const int RPB = 256 / C;
  int t = threadIdx.x;
  int c = t % C, rg = t / C;
  float s = 0.f, sq = 0.f;
  for (long long row = (long long)blockIdx.x * RPB + rg; row < N_NODES;
       row += (long long)gridDim.x * RPB) {
    float v = BF ? bf2f(((const u16*)yv)[row * C + c])
                 : ((const float*)yv)[row * C + c];
    s += v; sq += v * v;
  }
  __shared__ float ls[256], lq[256];
  ls[t] = s; lq[t] = sq;
  __syncthreads();
  if (t < C) {
    float S = 0.f, Q = 0.f;
    for (int g = 0; g < RPB; g++) { S += ls[g * C + t]; Q += lq[g * C + t]; }
    atomicAdd(&sums[t], S);
    atomicAdd(&sums[C + t], Q);
  }
}

// fold BN into affine: ac[c]=a, ac[C+c]=c  with  a=g*rsqrt(var+eps), c=b-mean*a
__global__ void finalize_kernel(const float* __restrict__ sums, const float* __restrict__ g,
                                const float* __restrict__ b, float* __restrict__ ac, int C) {
  int t = threadIdx.x;
  if (t < C) {
    float inv = 1.f / (float)N_NODES;
    float mean = sums[t] * inv;
    float var = sums[C + t] * inv - mean * mean;
    float a = g[t] * rsqrtf(var + 1e-3f);
    ac[t] = a;
    ac[C + t] = b[t] - mean * a;
  }
}

// in-place bf16 BN+ReLU for C=64 buffers
__global__ __launch_bounds__(256) void apply_bn_relu_kernel(u16* __restrict__ y,
                                                            const float* __restrict__ ac) {
  __shared__ float a[64], cc[64];
  int t = threadIdx.x;
  if (t < 64) { a[t] = ac[t]; cc[t] = ac[64 + t]; }
  __syncthreads();
  const long long total = (long long)N_NODES * 64 / 8;
  for (long long i = (long long)blockIdx.x * 256 + t; i < total;
       i += (long long)gridDim.x * 256) {
    uint4 u = ((uint4*)y)[i];
    int c0 = (int)((i & 7) * 8);
    u16* us = (u16*)&u;
    #pragma unroll
    for (int j = 0; j < 8; j++) {
      float v = bf2f(us[j]);
      v = fmaf(a[c0 + j], v, cc[c0 + j]);
      us[j] = f2bf(fmaxf(v, 0.f));
    }
    ((uint4*)y)[i] = u;
  }
}

// out = relu(BN3(y3) + x), in place on d_out
__global__ __launch_bounds__(256) void epilogue_kernel(float* __restrict__ y3,
                                                       const float* __restrict__ x,
                                                       const float* __restrict__ ac) {
  __shared__ float a[256], cc[256];
  int t = threadIdx.x;
  a[t] = ac[t]; cc[t] = ac[256 + t];
  __syncthreads();
  const long long total = (long long)N_NODES * 256 / 4;
  for (long long i = (long long)blockIdx.x * 256 + t; i < total;
       i += (long long)gridDim.x * 256) {
    floatx4 v = ((floatx4*)y3)[i];
    floatx4 xi = ((const floatx4*)x)[i];
    int c0 = (int)((i & 63) * 4);
    #pragma unroll
    for (int j = 0; j < 4; j++) {
      float r = fmaf(a[c0 + j], v[j], cc[c0 + j]) + xi[j];
      v[j] = fmaxf(r, 0.f);
    }
    ((floatx4*)y3)[i] = v;
  }
}

// ---------------------------------------------------------------------------
extern "C" void kernel_launch(void* const* d_in, const int* in_sizes, int n_in,
                              void* d_out, int out_size, void* d_ws, size_t ws_size,
                              hipStream_t stream) {
  (void)in_sizes; (void)n_in; (void)out_size; (void)ws_size;
  const float* x  = (const float*)d_in[0];
  const int* neigh = (const int*)d_in[1];
  const float* W1 = (const float*)d_in[3];
  const float* g1 = (const float*)d_in[4];
  const float* b1 = (const float*)d_in[5];
  const float* W2 = (const float*)d_in[6];
  const float* g2 = (const float*)d_in[7];
  const float* b2 = (const float*)d_in[8];
  const float* W3 = (const float*)d_in[9];
  const float* g3 = (const float*)d_in[10];
  const float* b3 = (const float*)d_in[11];

  char* ws = (char*)d_ws;
  u16* h1  = (u16*)(ws);                          // N*64 bf16 = 25,600,000 B
  u16* h2  = (u16*)(ws + 25600000LL);             // N*64 bf16
  u16* w1t = (u16*)(ws + 51200000LL);             // 32,768 B
  u16* w2t = (u16*)(ws + 51232768LL);             // 221,184 B
  u16* w3t = (u16*)(ws + 51453952LL);             // 32,768 B
  float* stats = (float*)(ws + 51486720LL);       // 1536 floats
  float* s1 = stats,        *ac1 = stats + 128;
  float* s2 = stats + 256,  *ac2 = stats + 384;
  float* s3 = stats + 512,  *ac3 = stats + 1024;
  float* y3 = (float*)d_out;

  const int MB = N_NODES / 64;  // 3125 row-tiles

  prep_kernel<<<256, 256, 0, stream>>>(W1, W2, W3, w1t, w2t, w3t, stats);

  gemm1_kernel<<<MB, 256, 0, stream>>>(x, w1t, h1);
  stats_kernel<64, true><<<1024, 256, 0, stream>>>(h1, s1);
  finalize_kernel<<<1, 256, 0, stream>>>(s1, g1, b1, ac1, 64);
  apply_bn_relu_kernel<<<2048, 256, 0, stream>>>(h1, ac1);

  gemm2_kernel<<<MB, 256, 0, stream>>>(h1, neigh, w2t, h2);
  stats_kernel<64, true><<<1024, 256, 0, stream>>>(h2, s2);
  finalize_kernel<<<1, 256, 0, stream>>>(s2, g2, b2, ac2, 64);
  apply_bn_relu_kernel<<<2048, 256, 0, stream>>>(h2, ac2);

  gemm3_kernel<<<MB, 256, 0, stream>>>(h2, w3t, y3);
  stats_kernel<256, false><<<2048, 256, 0, stream>>>(y3, s3);
  finalize_kernel<<<1, 256, 0, stream>>>(s3, g3, b3, ac3, 256);
  epilogue_kernel<<<4096, 256, 0, stream>>>(y3, x, ac3);
}